// Round 11
// baseline (130.945 us; speedup 1.0000x reference)
//
#include <hip/hip_runtime.h>
#include <stdint.h>

#define Bsz 16384
#define Hh  512
#define Kd  1024      // I + H
#define BM  128       // M rows per workgroup
#define BNJ 32        // j columns per workgroup (x5 gates)
#define BK  32        // K per tile
#define NT  32        // K tiles

// LDS: 4 A bufs (8KB @ b*8192) + 4 B bufs (10KB @ 32768 + b*10240) = 72KB -> 2 wg/CU
#define AOFF(b) ((b) * 8192)
#define BOFF(b) ((b) * 10240)

typedef __attribute__((ext_vector_type(8))) short bf16x8;
typedef __attribute__((ext_vector_type(4))) float f32x4;
typedef __attribute__((ext_vector_type(8))) unsigned short u16x8;

__device__ __forceinline__ unsigned short f2bf(float f) {
    union { float f; unsigned u; } v; v.f = f;
    unsigned u = v.u;
    return (unsigned short)((u + 0x7fffu + ((u >> 16) & 1u)) >> 16);
}
__device__ __forceinline__ float fast_tanh(float x) {
    float e = __expf(2.f * x);
    return (e - 1.f) / (e + 1.f);
}
__device__ __forceinline__ float fast_sigmoid(float x) {
    return 1.f / (1.f + __expf(-x));
}

// ---------------- pack A = [x | h_prev] -> bf16 [16384][1024] ----------------
__global__ void pack_A(const float* __restrict__ x, const float* __restrict__ h,
                       unsigned short* __restrict__ A) {
    const long total = (long)Bsz * Kd / 8;
    for (long i = (long)blockIdx.x * blockDim.x + threadIdx.x; i < total;
         i += (long)gridDim.x * blockDim.x) {
        long row = i >> 7;
        int  col = ((int)(i & 127)) << 3;
        const float* src = (col < 512) ? (x + row * 512 + col)
                                       : (h + row * 512 + (col - 512));
        float4 f0 = *(const float4*)(src);
        float4 f1 = *(const float4*)(src + 4);
        u16x8 o;
        o[0]=f2bf(f0.x); o[1]=f2bf(f0.y); o[2]=f2bf(f0.z); o[3]=f2bf(f0.w);
        o[4]=f2bf(f1.x); o[5]=f2bf(f1.y); o[6]=f2bf(f1.z); o[7]=f2bf(f1.w);
        *(u16x8*)(A + (i << 3)) = o;
    }
}

// ---- pack B into fragment-linear layout ----
// elem addr = jgrp*81920 + g*16384 + kt*1024 + kh*512 + l*8 + e
//  = W[g][ j = jgrp*16 + (l&15) ][ k = kt*64 + kh*32 + (l>>4)*8 + e ]
// BK=32 tile T: unit base = jgrp*81920 + g*16384 + T*512 (elems)
__global__ void pack_B(const float* __restrict__ Wxi, const float* __restrict__ Whi,
                       const float* __restrict__ Wxf, const float* __restrict__ Whf,
                       const float* __restrict__ Wxc, const float* __restrict__ Whc,
                       const float* __restrict__ Wxo, const float* __restrict__ Who,
                       const float* __restrict__ We,
                       const float* __restrict__ bxi, const float* __restrict__ bhi,
                       const float* __restrict__ bxf, const float* __restrict__ bhf,
                       const float* __restrict__ bxc, const float* __restrict__ bhc,
                       const float* __restrict__ bxo, const float* __restrict__ bho,
                       const float* __restrict__ be,
                       unsigned short* __restrict__ Bp, float* __restrict__ bias) {
    const long id = (long)blockIdx.x * blockDim.x + threadIdx.x;  // 327680 total
    if (id < 327680) {
        int blk = (int)(id >> 6);
        int l   = (int)(id & 63);
        int kh  = blk & 1;
        int kt  = (blk >> 1) & 15;
        int rest = blk >> 5;
        int g    = rest % 5;
        int jgrp = rest / 5;
        int j  = jgrp * 16 + (l & 15);
        int k0 = kt * 64 + kh * 32 + ((l >> 4) << 3);
        const float* src;
        if (g == 4) {
            src = We + (long)j * 1024 + k0;
        } else {
            const float* Wx = (g == 0) ? Wxi : (g == 1) ? Wxf : (g == 2) ? Wxc : Wxo;
            const float* Wh = (g == 0) ? Whi : (g == 1) ? Whf : (g == 2) ? Whc : Who;
            src = (k0 < 512) ? (Wx + (long)j * 512 + k0)
                             : (Wh + (long)j * 512 + (k0 - 512));
        }
        float4 f0 = *(const float4*)(src);
        float4 f1 = *(const float4*)(src + 4);
        u16x8 o;
        o[0]=f2bf(f0.x); o[1]=f2bf(f0.y); o[2]=f2bf(f0.z); o[3]=f2bf(f0.w);
        o[4]=f2bf(f1.x); o[5]=f2bf(f1.y); o[6]=f2bf(f1.z); o[7]=f2bf(f1.w);
        *(u16x8*)(Bp + (long)blk * 512 + l * 8) = o;
    }
    if (id < 2560) {
        int row = (int)id;
        int g = row >> 9, j = row & 511;
        float b;
        if (g == 4) b = be[j];
        else {
            const float* bx = (g == 0) ? bxi : (g == 1) ? bxf : (g == 2) ? bxc : bxo;
            const float* bh = (g == 0) ? bhi : (g == 1) ? bhf : (g == 2) ? bhc : bho;
            b = bx[j] + bh[j];
        }
        bias[row] = b;
    }
}

// ------- fused GEMM: depth-3 staging (4 bufs), cross-tile frag pipeline, 2 wg/CU -------
#define GL16(g, l) __builtin_amdgcn_global_load_lds( \
    (const __attribute__((address_space(1))) unsigned int*)(g), \
    (__attribute__((address_space(3))) unsigned int*)(l), 16, 0, 0)

#define VM_I(n)    asm volatile("s_waitcnt vmcnt(" #n ")" ::: "memory")
#define VM(n)      VM_I(n)
#define LGKM_I(n)  asm volatile("s_waitcnt lgkmcnt(" #n ")" ::: "memory")
#define LGKM(n)    LGKM_I(n)
#define BARRIER()  asm volatile("s_barrier" ::: "memory")
#define SCHED0()   __builtin_amdgcn_sched_barrier(0)

#define MF(a, b, c) __builtin_amdgcn_mfma_f32_16x16x32_bf16(a, b, c, 0, 0, 0)

// read tile frags (buffer RB) into named set S (aS0..3, bS0..4): 9 ds_read_b128
#define RD9(S, RB) do { \
    a##S##0 = *(const bf16x8*)(aRP + AOFF(RB) + 0 * 1024); \
    a##S##1 = *(const bf16x8*)(aRP + AOFF(RB) + 1 * 1024); \
    a##S##2 = *(const bf16x8*)(aRP + AOFF(RB) + 2 * 1024); \
    a##S##3 = *(const bf16x8*)(aRP + AOFF(RB) + 3 * 1024); \
    b##S##0 = *(const bf16x8*)(bRP + BOFF(RB) + 0 * 1024); \
    b##S##1 = *(const bf16x8*)(bRP + BOFF(RB) + 1 * 1024); \
    b##S##2 = *(const bf16x8*)(bRP + BOFF(RB) + 2 * 1024); \
    b##S##3 = *(const bf16x8*)(bRP + BOFF(RB) + 3 * 1024); \
    b##S##4 = *(const bf16x8*)(bRP + BOFF(RB) + 4 * 1024); \
} while (0)

#define MF4(S, G) \
    acc[G][0] = MF(a##S##0, b##S##G, acc[G][0]); \
    acc[G][1] = MF(a##S##1, b##S##G, acc[G][1]); \
    acc[G][2] = MF(a##S##2, b##S##G, acc[G][2]); \
    acc[G][3] = MF(a##S##3, b##S##G, acc[G][3]);

#define MFMA20(S) do { \
    __builtin_amdgcn_s_setprio(1); \
    MF4(S, 0) MF4(S, 1) MF4(S, 2) MF4(S, 3) MF4(S, 4) \
    __builtin_amdgcn_s_setprio(0); \
} while (0)

// stage tile T into buffer SB: 2 A-chunks + 3 B-units per thread (5 GL16, uniform)
#define SG5(SB, T) do { \
    GL16(asg0 + (T) * 32,  lds_raw + AOFF(SB) + adst0); \
    GL16(asg1 + (T) * 32,  lds_raw + AOFF(SB) + adst1); \
    GL16(bsg0 + (T) * 512, lds_raw + 32768 + BOFF(SB) + bdo0); \
    GL16(bsg1 + (T) * 512, lds_raw + 32768 + BOFF(SB) + bdo1); \
    GL16(bsg2 + (T) * 512, lds_raw + 32768 + BOFF(SB) + bdo2); \
} while (0)

// steady tile t: compute set SC (tile t), prefetch frags of t+1 (buf RB) into SN,
// stage t+3 into SB, certify t+2 with vmcnt(5) (never 0), one barrier.
#define STEP(SC, SN, RB, SB, T) do { \
    SG5(SB, (T) + 3); \
    RD9(SN, RB); \
    LGKM(9); SCHED0(); \
    MFMA20(SC); \
    VM(5); BARRIER(); \
} while (0)

__global__ __launch_bounds__(256, 2)
void xlstm_gemm(const unsigned short* __restrict__ A,
                const unsigned short* __restrict__ Bp,
                const float* __restrict__ bias,
                const float* __restrict__ c_prev,
                float* __restrict__ out) {
    __shared__ __align__(16) unsigned char lds_raw[73728];  // 72 KB

    const int tid  = threadIdx.x;
    const int wid  = tid >> 6;
    const int lane = tid & 63;
    const int wm   = wid >> 1;    // 0..1 : M half (64 rows)
    const int wj   = wid & 1;     // 0..1 : j half (16 cols)
    const int fr   = lane & 15;
    const int q    = lane >> 4;

    // T1: bijective XCD swizzle (nwg = 2048, 2048 % 8 == 0)
    const int orig = blockIdx.x;
    const int wg   = (orig & 7) * 256 + (orig >> 3);
    const int mblk = wg >> 4;     // 0..127
    const int jblk = wg & 15;     // 0..15
    const long brow = (long)mblk * BM;
    const int  bcol = jblk * BNJ;

    f32x4 acc[5][4];
#pragma unroll
    for (int g = 0; g < 5; ++g)
#pragma unroll
        for (int m = 0; m < 4; ++m)
#pragma unroll
            for (int r = 0; r < 4; ++r) acc[g][m][r] = 0.f;

    // two named fragment sets (rule 20: no runtime-indexed arrays)
    bf16x8 aP0, aP1, aP2, aP3, bP0, bP1, bP2, bP3, bP4;
    bf16x8 aQ0, aQ1, aQ2, aQ3, bQ0, bQ1, bQ2, bQ3, bQ4;

    // ---- read-side LDS pointers (R8-proven layout) ----
    const unsigned char* aRP = lds_raw + wm * 4096 + fr * 64
                               + ((q ^ ((fr >> 1) & 3)) << 4);
    const unsigned char* bRP = lds_raw + 32768 + wj * 5120 + lane * 16;

    // ---- staging pointers (R8-proven) ----
    const int arow = tid >> 2;
    const unsigned short* asg0 = A + (brow + arow) * 1024L
                                   + (((tid & 3) ^ ((arow >> 1) & 3)) << 3);
    const unsigned short* asg1 = asg0 + 65536;   // row + 64
    const int adst0 = tid * 16;
    const int adst1 = tid * 16 + 4096;
    const unsigned short *bsg0, *bsg1, *bsg2;
    int bdo0, bdo1, bdo2;
#define BSTG_INIT(i) do { \
    int u_ = wid + 4 * (i); if (u_ >= 10) u_ -= 10; \
    int jl_ = u_ / 5; int g_ = u_ - 5 * jl_; \
    bsg##i = Bp + (long)(jblk * 2 + jl_) * 81920 + g_ * 16384 + lane * 8; \
    bdo##i = u_ * 1024 + lane * 16; \
} while (0)
    BSTG_INIT(0); BSTG_INIT(1); BSTG_INIT(2);
#undef BSTG_INIT

    // ---- prologue: stage tiles 0,1,2 -> bufs 0,1,2; certify 0,1; prefetch frags(0) ----
    SG5(0, 0);
    SG5(1, 1);
    SG5(2, 2);
    VM(5);           // tiles 0,1 certified; tile 2's 5 in flight
    BARRIER();
    RD9(P, 0);       // frags of tile 0 -> set P

    // ---- main loop ----
    // tile t: MFMA on set (t&1 ? Q : P); RD9(t+1) from buf (t+1)&3 into other set;
    // SG5(t+3) into buf (t+3)&3; VM(5) certifies t+2; 1 barrier.
    for (int tq = 0; tq < 28; tq += 4) {
        STEP(P, Q, 1, 3, tq + 0);
        STEP(Q, P, 2, 0, tq + 1);
        STEP(P, Q, 3, 1, tq + 2);
        STEP(Q, P, 0, 2, tq + 3);
    }
    // t=28 (stages tile 31, certifies 30)
    SG5(3, 31);
    RD9(Q, 1);
    LGKM(9); SCHED0();
    MFMA20(P);
    VM(5); BARRIER();
    // t=29 (certify 31: full drain of remaining staging)
    RD9(P, 2);
    LGKM(9); SCHED0();
    MFMA20(Q);
    VM(0); BARRIER();
    // t=30
    RD9(Q, 3);
    LGKM(9); SCHED0();
    MFMA20(P);
    // t=31
    LGKM(0); SCHED0();
    MFMA20(Q);

    // ---------------- epilogue (fused, in-register) ----------------
    const int j = bcol + wj * 16 + fr;
    const float bi_ = bias[j];
    const float bf_ = bias[512 + j];
    const float bc_ = bias[1024 + j];
    const float bo_ = bias[1536 + j];
    const float be_ = bias[2048 + j];
    const long mbase = brow + wm * 64 + (q << 2);
#pragma unroll
    for (int m = 0; m < 4; ++m) {
#pragma unroll
        for (int r = 0; r < 4; ++r) {
            long row = mbase + m * 16 + r;
            float gi = acc[0][m][r] + bi_;
            float gf = acc[1][m][r] + bf_;
            float gc = acc[2][m][r] + bc_;
            float go = acc[3][m][r] + bo_;
            float ge = acc[4][m][r] + be_;
            float iv = fast_sigmoid(gi);
            float fv = fast_sigmoid(gf);
            float gv = fast_tanh(gc);
            float ov = fast_sigmoid(go);
            float ef = __expf(fast_tanh(ge));
            float cp = c_prev[row * 512 + j];
            float cv = fv * cp + iv * gv;
            float hv = ov * fast_tanh(cv) * ef;
            out[row * 512 + j] = hv;
            out[(long)Bsz * 512 + row * 512 + j] = cv;
        }
    }
}

extern "C" void kernel_launch(void* const* d_in, const int* in_sizes, int n_in,
                              void* d_out, int out_size, void* d_ws, size_t ws_size,
                              hipStream_t stream) {
    const float* x      = (const float*)d_in[0];
    const float* h_prev = (const float*)d_in[1];
    const float* c_prev = (const float*)d_in[2];
    const float* Wxi = (const float*)d_in[3];
    const float* bxi = (const float*)d_in[4];
    const float* Whi = (const float*)d_in[5];
    const float* bhi = (const float*)d_in[6];
    const float* Wxf = (const float*)d_in[7];
    const float* bxf = (const float*)d_in[8];
    const float* Whf = (const float*)d_in[9];
    const float* bhf = (const float*)d_in[10];
    const float* Wxc = (const float*)d_in[11];
    const float* bxc = (const float*)d_in[12];
    const float* Whc = (const float*)d_in[13];
    const float* bhc = (const float*)d_in[14];
    const float* Wxo = (const float*)d_in[15];
    const float* bxo = (const float*)d_in[16];
    const float* Who = (const float*)d_in[17];
    const float* bho = (const float*)d_in[18];
    const float* We  = (const float*)d_in[19];
    const float* be  = (const float*)d_in[20];

    unsigned short* Abf  = (unsigned short*)d_ws;                        // 33,554,432 B
    unsigned short* Bp   = (unsigned short*)((char*)d_ws + 33554432);    //  5,242,880 B
    float*          bias = (float*)((char*)d_ws + 33554432 + 5242880);   //     10,240 B

    pack_A<<<2048, 256, 0, stream>>>(x, h_prev, Abf);
    pack_B<<<1280, 256, 0, stream>>>(Wxi, Whi, Wxf, Whf, Wxc, Whc, Wxo, Who, We,
                                     bxi, bhi, bxf, bhf, bxc, bhc, bxo, bho, be,
                                     Bp, bias);
    xlstm_gemm<<<2048, 256, 0, stream>>>(Abf, Bp, bias, c_prev, (float*)d_out);
}

// Round 12
// 118.463 us; speedup vs baseline: 1.1054x; 1.1054x over previous
//
#include <hip/hip_runtime.h>
#include <stdint.h>

#define Bsz 16384
#define Hh  512
#define Kd  1024      // I + H
#define BM  128       // M rows per workgroup
#define BNJ 32        // j columns per workgroup (x5 gates)
#define BK  32        // K per tile
#define NT  32        // K tiles

typedef __attribute__((ext_vector_type(8))) short bf16x8;
typedef __attribute__((ext_vector_type(4))) float f32x4;
typedef __attribute__((ext_vector_type(8))) unsigned short u16x8;

__device__ __forceinline__ unsigned short f2bf(float f) {
    union { float f; unsigned u; } v; v.f = f;
    unsigned u = v.u;
    return (unsigned short)((u + 0x7fffu + ((u >> 16) & 1u)) >> 16);
}
__device__ __forceinline__ float fast_tanh(float x) {
    float e = __expf(2.f * x);
    return (e - 1.f) / (e + 1.f);
}
__device__ __forceinline__ float fast_sigmoid(float x) {
    return 1.f / (1.f + __expf(-x));
}

// ---- pack A fragment-linear: unit blk = (mblk*32 + t)*8 + u  (1 KB units) ----
// elem blk*512 + l*8 + e = A[mblk*128 + u*16 + (l&15)][t*32 + (l>>4)*8 + e]
// where A[r][k] = x[r][k] (k<512) else h_prev[r][k-512]
__global__ void pack_A(const float* __restrict__ x, const float* __restrict__ h,
                       unsigned short* __restrict__ A) {
    const long total = (long)Bsz * Kd / 8;   // 2,097,152 units of 8
    for (long i = (long)blockIdx.x * blockDim.x + threadIdx.x; i < total;
         i += (long)gridDim.x * blockDim.x) {
        int  l    = (int)(i & 63);
        long blk  = i >> 6;
        int  u    = (int)(blk & 7);
        int  t    = (int)((blk >> 3) & 31);
        long mblk = blk >> 8;
        long row  = mblk * 128 + u * 16 + (l & 15);
        int  k0   = t * 32 + ((l >> 4) << 3);
        const float* src = (k0 < 512) ? (x + row * 512 + k0)
                                      : (h + row * 512 + (k0 - 512));
        float4 f0 = *(const float4*)(src);
        float4 f1 = *(const float4*)(src + 4);
        u16x8 o;
        o[0]=f2bf(f0.x); o[1]=f2bf(f0.y); o[2]=f2bf(f0.z); o[3]=f2bf(f0.w);
        o[4]=f2bf(f1.x); o[5]=f2bf(f1.y); o[6]=f2bf(f1.z); o[7]=f2bf(f1.w);
        *(u16x8*)(A + (i << 3)) = o;
    }
}

// ---- pack B into fragment-linear layout (unchanged, proven) ----
// elem addr = jgrp*81920 + g*16384 + kt*1024 + kh*512 + l*8 + e
//  = W[g][ j = jgrp*16 + (l&15) ][ k = kt*64 + kh*32 + (l>>4)*8 + e ]
// BK=32 tile T: unit base = jgrp*81920 + g*16384 + T*512 (elems)
__global__ void pack_B(const float* __restrict__ Wxi, const float* __restrict__ Whi,
                       const float* __restrict__ Wxf, const float* __restrict__ Whf,
                       const float* __restrict__ Wxc, const float* __restrict__ Whc,
                       const float* __restrict__ Wxo, const float* __restrict__ Who,
                       const float* __restrict__ We,
                       const float* __restrict__ bxi, const float* __restrict__ bhi,
                       const float* __restrict__ bxf, const float* __restrict__ bhf,
                       const float* __restrict__ bxc, const float* __restrict__ bhc,
                       const float* __restrict__ bxo, const float* __restrict__ bho,
                       const float* __restrict__ be,
                       unsigned short* __restrict__ Bp, float* __restrict__ bias) {
    const long id = (long)blockIdx.x * blockDim.x + threadIdx.x;  // 327680 total
    if (id < 327680) {
        int blk = (int)(id >> 6);
        int l   = (int)(id & 63);
        int kh  = blk & 1;
        int kt  = (blk >> 1) & 15;
        int rest = blk >> 5;
        int g    = rest % 5;
        int jgrp = rest / 5;
        int j  = jgrp * 16 + (l & 15);
        int k0 = kt * 64 + kh * 32 + ((l >> 4) << 3);
        const float* src;
        if (g == 4) {
            src = We + (long)j * 1024 + k0;
        } else {
            const float* Wx = (g == 0) ? Wxi : (g == 1) ? Wxf : (g == 2) ? Wxc : Wxo;
            const float* Wh = (g == 0) ? Whi : (g == 1) ? Whf : (g == 2) ? Whc : Who;
            src = (k0 < 512) ? (Wx + (long)j * 512 + k0)
                             : (Wh + (long)j * 512 + (k0 - 512));
        }
        float4 f0 = *(const float4*)(src);
        float4 f1 = *(const float4*)(src + 4);
        u16x8 o;
        o[0]=f2bf(f0.x); o[1]=f2bf(f0.y); o[2]=f2bf(f0.z); o[3]=f2bf(f0.w);
        o[4]=f2bf(f1.x); o[5]=f2bf(f1.y); o[6]=f2bf(f1.z); o[7]=f2bf(f1.w);
        *(u16x8*)(Bp + (long)blk * 512 + l * 8) = o;
    }
    if (id < 2560) {
        int row = (int)id;
        int g = row >> 9, j = row & 511;
        float b;
        if (g == 4) b = be[j];
        else {
            const float* bx = (g == 0) ? bxi : (g == 1) ? bxf : (g == 2) ? bxc : bxo;
            const float* bh = (g == 0) ? bhi : (g == 1) ? bhf : (g == 2) ? bhc : bho;
            b = bx[j] + bh[j];
        }
        bias[row] = b;
    }
}

// ---- fused GEMM: A global->reg (frag-linear, 2 banks), B in LDS (2 bufs), 3 wg/CU ----
#define GL16(g, l) __builtin_amdgcn_global_load_lds( \
    (const __attribute__((address_space(1))) unsigned int*)(g), \
    (__attribute__((address_space(3))) unsigned int*)(l), 16, 0, 0)

#define VM_I(n)    asm volatile("s_waitcnt vmcnt(" #n ")" ::: "memory")
#define VM(n)      VM_I(n)
#define BARRIER()  asm volatile("s_barrier" ::: "memory")

#define MF(a, b, c) __builtin_amdgcn_mfma_f32_16x16x32_bf16(a, b, c, 0, 0, 0)

// B frags from LDS (plain C loads -> compiler emits fine-grained lgkm waits)
#define RDB5(RBO) do { \
    bq0 = *(const bf16x8*)(bRP + (RBO) + 0 * 1024); \
    bq1 = *(const bf16x8*)(bRP + (RBO) + 1 * 1024); \
    bq2 = *(const bf16x8*)(bRP + (RBO) + 2 * 1024); \
    bq3 = *(const bf16x8*)(bRP + (RBO) + 3 * 1024); \
    bq4 = *(const bf16x8*)(bRP + (RBO) + 4 * 1024); \
} while (0)

#define MF4(S, BQ, G) \
    acc[G][0] = MF(a##S##0, BQ, acc[G][0]); \
    acc[G][1] = MF(a##S##1, BQ, acc[G][1]); \
    acc[G][2] = MF(a##S##2, BQ, acc[G][2]); \
    acc[G][3] = MF(a##S##3, BQ, acc[G][3]);

#define MFMA20(S) do { \
    __builtin_amdgcn_s_setprio(1); \
    MF4(S, bq0, 0) MF4(S, bq1, 1) MF4(S, bq2, 2) MF4(S, bq3, 3) MF4(S, bq4, 4) \
    __builtin_amdgcn_s_setprio(0); \
} while (0)

// A frag loads for tile T into bank S (4 x global_load_dwordx4, coalesced 1KB units)
#define LOADA4(S, T) do { \
    asm volatile("global_load_dwordx4 %0, %1, off" : "=v"(a##S##0) : "v"(asrc + (T) * 4096L + 0 * 512)); \
    asm volatile("global_load_dwordx4 %0, %1, off" : "=v"(a##S##1) : "v"(asrc + (T) * 4096L + 1 * 512)); \
    asm volatile("global_load_dwordx4 %0, %1, off" : "=v"(a##S##2) : "v"(asrc + (T) * 4096L + 2 * 512)); \
    asm volatile("global_load_dwordx4 %0, %1, off" : "=v"(a##S##3) : "v"(asrc + (T) * 4096L + 3 * 512)); \
} while (0)

// stage B tile T into LDS buf at byte SBO: 3 GL16 per thread
#define SGB3(SBO, T) do { \
    GL16(bsg0 + (T) * 512, lds_raw + (SBO) + bdo0); \
    GL16(bsg1 + (T) * 512, lds_raw + (SBO) + bdo1); \
    GL16(bsg2 + (T) * 512, lds_raw + (SBO) + bdo2); \
} while (0)

// one K-tile: stage B(t+1), read B(t) frags, 20 MFMA on A-bank, issue A(t+2),
// counted vmcnt(4) (certifies A(t+1)+B(t+1), leaves A(t+2) in flight), 1 barrier
#define STEP(T, S, RBO, SBO) do { \
    SGB3(SBO, (T) + 1); \
    RDB5(RBO); \
    MFMA20(S); \
    LOADA4(S, (T) + 2); \
    VM(4); BARRIER(); \
} while (0)

__global__ __launch_bounds__(256, 3)
void xlstm_gemm(const unsigned short* __restrict__ Apk,
                const unsigned short* __restrict__ Bp,
                const float* __restrict__ bias,
                const float* __restrict__ c_prev,
                float* __restrict__ out) {
    __shared__ __align__(16) unsigned char lds_raw[20480];  // 2 x 10 KB (B only)

    const int tid  = threadIdx.x;
    const int wid  = tid >> 6;
    const int lane = tid & 63;
    const int wm   = wid >> 1;    // 0..1 : M half (64 rows)
    const int wj   = wid & 1;     // 0..1 : j half (16 cols)
    const int fr   = lane & 15;
    const int q    = lane >> 4;

    // T1: bijective XCD swizzle (nwg = 2048, 2048 % 8 == 0)
    const int orig = blockIdx.x;
    const int wg   = (orig & 7) * 256 + (orig >> 3);
    const int mblk = wg >> 4;     // 0..127
    const int jblk = wg & 15;     // 0..15
    const long brow = (long)mblk * BM;
    const int  bcol = jblk * BNJ;

    f32x4 acc[5][4];
#pragma unroll
    for (int g = 0; g < 5; ++g)
#pragma unroll
        for (int m = 0; m < 4; ++m)
#pragma unroll
            for (int r = 0; r < 4; ++r) acc[g][m][r] = 0.f;

    // named A banks (rule 20) + B frags
    bf16x8 aP0, aP1, aP2, aP3;
    bf16x8 aQ0, aQ1, aQ2, aQ3;
    bf16x8 bq0, bq1, bq2, bq3, bq4;

    // ---- A source base: units (mblk*32 + t)*8 + wm*4 + i, lane's 16B at lane*8 ----
    const unsigned short* asrc = Apk + (long)mblk * 131072 + wm * 2048 + lane * 8;

    // ---- B read pointer (LDS) ----
    const unsigned char* bRP = lds_raw + wj * 5120 + lane * 16;

    // ---- B staging pointers (R8-proven: unit u = wid + 4i, wrap dups benign) ----
    const unsigned short *bsg0, *bsg1, *bsg2;
    int bdo0, bdo1, bdo2;
#define BSTG_INIT(i) do { \
    int u_ = wid + 4 * (i); if (u_ >= 10) u_ -= 10; \
    int jl_ = u_ / 5; int g_ = u_ - 5 * jl_; \
    bsg##i = Bp + (long)(jblk * 2 + jl_) * 81920 + g_ * 16384 + lane * 8; \
    bdo##i = u_ * 1024 + lane * 16; \
} while (0)
    BSTG_INIT(0); BSTG_INIT(1); BSTG_INIT(2);
#undef BSTG_INIT

    // ---- prologue: B(0)->buf0, A(0)->P, A(1)->Q; certify B(0)+A(0) ----
    SGB3(0, 0);
    LOADA4(P, 0);
    LOADA4(Q, 1);
    VM(4);           // completes B0(3)+A0(4); A1's 4 in flight
    BARRIER();

    // ---- main loop: tiles 0..29; B(t) in buf t&1; A(t) in bank t&1 ----
    for (int t = 0; t < 30; t += 2) {
        STEP(t,     P, 0,     10240);
        STEP(t + 1, Q, 10240, 0);
    }
    // t=30: stage B(31)->buf1, full drain (A31 + B31), barrier
    SGB3(10240, 31);
    RDB5(0);
    MFMA20(P);
    VM(0); BARRIER();
    // t=31: compute only
    RDB5(10240);
    MFMA20(Q);

    // ---------------- epilogue (fused, in-register) ----------------
    const int j = bcol + wj * 16 + fr;
    const float bi_ = bias[j];
    const float bf_ = bias[512 + j];
    const float bc_ = bias[1024 + j];
    const float bo_ = bias[1536 + j];
    const float be_ = bias[2048 + j];
    const long mbase = brow + wm * 64 + (q << 2);
#pragma unroll
    for (int m = 0; m < 4; ++m) {
#pragma unroll
        for (int r = 0; r < 4; ++r) {
            long row = mbase + m * 16 + r;
            float gi = acc[0][m][r] + bi_;
            float gf = acc[1][m][r] + bf_;
            float gc = acc[2][m][r] + bc_;
            float go = acc[3][m][r] + bo_;
            float ge = acc[4][m][r] + be_;
            float iv = fast_sigmoid(gi);
            float fv = fast_sigmoid(gf);
            float gv = fast_tanh(gc);
            float ov = fast_sigmoid(go);
            float ef = __expf(fast_tanh(ge));
            float cp = c_prev[row * 512 + j];
            float cv = fv * cp + iv * gv;
            float hv = ov * fast_tanh(cv) * ef;
            out[row * 512 + j] = hv;
            out[(long)Bsz * 512 + row * 512 + j] = cv;
        }
    }
}

extern "C" void kernel_launch(void* const* d_in, const int* in_sizes, int n_in,
                              void* d_out, int out_size, void* d_ws, size_t ws_size,
                              hipStream_t stream) {
    const float* x      = (const float*)d_in[0];
    const float* h_prev = (const float*)d_in[1];
    const float* c_prev = (const float*)d_in[2];
    const float* Wxi = (const float*)d_in[3];
    const float* bxi = (const float*)d_in[4];
    const float* Whi = (const float*)d_in[5];
    const float* bhi = (const float*)d_in[6];
    const float* Wxf = (const float*)d_in[7];
    const float* bxf = (const float*)d_in[8];
    const float* Whf = (const float*)d_in[9];
    const float* bhf = (const float*)d_in[10];
    const float* Wxc = (const float*)d_in[11];
    const float* bxc = (const float*)d_in[12];
    const float* Whc = (const float*)d_in[13];
    const float* bhc = (const float*)d_in[14];
    const float* Wxo = (const float*)d_in[15];
    const float* bxo = (const float*)d_in[16];
    const float* Who = (const float*)d_in[17];
    const float* bho = (const float*)d_in[18];
    const float* We  = (const float*)d_in[19];
    const float* be  = (const float*)d_in[20];

    unsigned short* Abf  = (unsigned short*)d_ws;                        // 33,554,432 B
    unsigned short* Bp   = (unsigned short*)((char*)d_ws + 33554432);    //  5,242,880 B
    float*          bias = (float*)((char*)d_ws + 33554432 + 5242880);   //     10,240 B

    pack_A<<<2048, 256, 0, stream>>>(x, h_prev, Abf);
    pack_B<<<1280, 256, 0, stream>>>(Wxi, Whi, Wxf, Whf, Wxc, Whc, Wxo, Who, We,
                                     bxi, bhi, bxf, bhf, bxc, bhc, bxo, bho, be,
                                     Bp, bias);
    xlstm_gemm<<<2048, 256, 0, stream>>>(Abf, Bp, bias, c_prev, (float*)d_out);
}